// Round 11
// baseline (264.221 us; speedup 1.0000x reference)
//
#include <hip/hip_runtime.h>

#define NN 50000
#define NE 800000
#define BKT 48        // bucket slots per node (dataset max in-degree ~45; guarded)

typedef short s8v  __attribute__((ext_vector_type(8)));   // 8 bf16 (4 VGPRs)
typedef float f4v  __attribute__((ext_vector_type(4)));   // MFMA acc

__device__ __forceinline__ unsigned f2bf(float f) {       // RNE pack
    unsigned u = __float_as_uint(f);
    return (u + 0x7fffu + ((u >> 16) & 1u)) >> 16;
}
__device__ __forceinline__ float bf2f_lo(unsigned u) { return __uint_as_float(u << 16); }
__device__ __forceinline__ float bf2f_hi(unsigned u) { return __uint_as_float(u & 0xffff0000u); }

__device__ __forceinline__ s8v pack8(float4 p, float4 q) {
    union { unsigned u[4]; s8v v; } r;
    r.u[0] = (f2bf(p.y) << 16) | f2bf(p.x);
    r.u[1] = (f2bf(p.w) << 16) | f2bf(p.z);
    r.u[2] = (f2bf(q.y) << 16) | f2bf(q.x);
    r.u[3] = (f2bf(q.w) << 16) | f2bf(q.z);
    return r.v;
}

// Build MFMA B-fragment in-register from fp32 W (used ONLY in k_fg's GEMM blocks,
// which have VGPR/latency slack; NOT in the agg kernels where it costs occupancy).
__device__ __forceinline__ s8v wfrag(const float* __restrict__ W, int ldw, int n, int kc) {
    const float* p = W + (size_t)kc * 8 * ldw + n;
    union { unsigned u[4]; s8v v; } r;
#pragma unroll
    for (int t = 0; t < 4; ++t)
        r.u[t] = (f2bf(p[(size_t)(2 * t + 1) * ldw]) << 16) | f2bf(p[(size_t)(2 * t) * ldw]);
    return r.v;
}

// ================= fused + INTERLEAVED: bucket CSR fill <-> GEMM-1 | Wt transpose =================
// blocks [0,7038): every 9th is a GEMM block (in-register W1 frags), rest are
// XCD-sliced int4 fill (R6-proven). blocks [7038,7166): transpose W2/proj -> bf16 Wt.
__global__ __launch_bounds__(256) void k_fg(const float4* __restrict__ x4,
                                            const float* __restrict__ W1,
                                            unsigned short* __restrict__ Hb,
                                            const int* __restrict__ src, const int* __restrict__ dst,
                                            int* __restrict__ cursor, int* __restrict__ esrc,
                                            const float* __restrict__ W2,
                                            const float* __restrict__ Wmu, const float* __restrict__ Wlv,
                                            unsigned short* __restrict__ Wt) {
    int b = blockIdx.x;
    if (b >= 7038) {
        int idx = (b - 7038) * 256 + (int)threadIdx.x;   // < 32768 = 2*16384 exactly
        int m = idx >> 14, i = idx & 16383;
        int n = i & 127, k = i >> 7;
        float v;
        if (m == 0) v = W2[k * 128 + n];
        else        v = (n < 64) ? Wmu[k * 64 + n] : Wlv[k * 64 + (n - 64)];
        Wt[m * 16384 + n * 128 + k] = (unsigned short)f2bf(v);
        return;
    }
    if (b % 9 != 8) {
        int fb = b - b / 9;                        // dense fill index [0, 6256)
        int xcd = fb & 7;                          // heuristic blockIdx%8 <-> XCD mapping
        int idx = (fb >> 3) * 256 + (int)threadIdx.x;
        if (idx >= NE / 4) return;
        int4 d4 = ((const int4*)dst)[idx];
        int4 s4 = ((const int4*)src)[idx];
        int dv[4] = { d4.x, d4.y, d4.z, d4.w };
        int sv[4] = { s4.x, s4.y, s4.z, s4.w };
#pragma unroll
        for (int k = 0; k < 4; ++k) {
            int d = dv[k];
            if (d / (NN / 8) == xcd) {             // atomic targets stay in one XCD's L2
                int p = atomicAdd(&cursor[d], 1);
                if (p < BKT) esrc[(size_t)d * BKT + p] = sv[k];
            }
        }
    } else {
        int bg = b / 9;                            // gemm index [0, 782)
        int wave = threadIdx.x >> 6, lane = threadIdx.x & 63;
        int quad = lane >> 4, l16 = lane & 15;
        int row0 = bg * 64 + wave * 16;
        int arow = row0 + l16;
        int arc  = arow < NN ? arow : NN - 1;      // clamp (stores guarded)

        const float4* xq = x4 + (size_t)arc * 32;  // 32 float4 per 128-ch row
        s8v a0 = pack8(xq[ 0 + quad * 2], xq[ 1 + quad * 2]);
        s8v a1 = pack8(xq[ 8 + quad * 2], xq[ 9 + quad * 2]);
        s8v a2 = pack8(xq[16 + quad * 2], xq[17 + quad * 2]);
        s8v a3 = pack8(xq[24 + quad * 2], xq[25 + quad * 2]);

        f4v acc[8];
#pragma unroll
        for (int c = 0; c < 8; ++c) acc[c] = (f4v)0.f;

#pragma unroll
        for (int c = 0; c < 8; ++c) {
            int n = c * 16 + l16;
            s8v w0 = wfrag(W1, 128, n, quad);
            s8v w1 = wfrag(W1, 128, n, 4 + quad);
            s8v w2 = wfrag(W1, 128, n, 8 + quad);
            s8v w3 = wfrag(W1, 128, n, 12 + quad);
            acc[c] = __builtin_amdgcn_mfma_f32_16x16x32_bf16(a0, w0, acc[c], 0, 0, 0);
            acc[c] = __builtin_amdgcn_mfma_f32_16x16x32_bf16(a1, w1, acc[c], 0, 0, 0);
            acc[c] = __builtin_amdgcn_mfma_f32_16x16x32_bf16(a2, w2, acc[c], 0, 0, 0);
            acc[c] = __builtin_amdgcn_mfma_f32_16x16x32_bf16(a3, w3, acc[c], 0, 0, 0);
        }

#pragma unroll
        for (int c = 0; c < 8; ++c) {
#pragma unroll
            for (int r = 0; r < 4; ++r) {
                int ro = row0 + quad * 4 + r;
                if (ro < NN) Hb[(size_t)ro * 128 + c * 16 + l16] = (unsigned short)f2bf(acc[c][r]);
            }
        }
    }
}

#define ACCUM(K) { float lo = bf2f_lo(u[K]), hi = bf2f_hi(u[K]);            \
    switch ((K) & 3) {                                                       \
        case 0: ax0 += lo * w[K]; ay0 += hi * w[K]; break;                   \
        case 1: ax1 += lo * w[K]; ay1 += hi * w[K]; break;                   \
        case 2: ax2 += lo * w[K]; ay2 += hi * w[K]; break;                   \
        default: ax3 += lo * w[K]; ay3 += hi * w[K]; break; } }

// ================= per-node aggregation (one full wave per node) — R6-proven =================
__device__ __forceinline__ float2 agg_node(const unsigned* __restrict__ h2,
                                           const int* __restrict__ degc,
                                           const int* __restrict__ esrc,
                                           const float* __restrict__ b,
                                           int n, int lane) {
    int d = __builtin_amdgcn_readfirstlane(degc[n]);
    float dn = rsqrtf((float)(d + 1));             // +1 = self loop
    int svr = esrc[(size_t)n * BKT + lane];        // whole bucket (lanes >= BKT spill into
                                                   // next bucket; only lanes < d consumed)
    unsigned suv = ((unsigned)svr < (unsigned)NN) ? (unsigned)svr : 0u;  // clamp garbage
    int dgv = degc[suv];                           // per-lane degree gather (64 parallel)
    float wsv = rsqrtf((float)(dgv + 1)) * dn;     // per-lane edge weight

    float ax0 = 0.f, ay0 = 0.f, ax1 = 0.f, ay1 = 0.f;
    float ax2 = 0.f, ay2 = 0.f, ax3 = 0.f, ay3 = 0.f;

    if (d <= 16) {   // short prologue: 16 masked gathers
        unsigned u[16];
        float    w[16];
#pragma unroll
        for (int k = 0; k < 16; ++k) {
            unsigned su = (unsigned)__builtin_amdgcn_readlane((int)suv, k);
            float wk = __int_as_float(__builtin_amdgcn_readlane(__float_as_int(wsv), k));
            w[k] = (k < d) ? wk : 0.f;
            u[k] = h2[(size_t)su * 64 + lane];
        }
#pragma unroll
        for (int k = 0; k < 16; ++k) ACCUM(k)
    } else {         // 24 masked gathers, all independent
        unsigned u[24];
        float    w[24];
#pragma unroll
        for (int k = 0; k < 24; ++k) {
            unsigned su = (unsigned)__builtin_amdgcn_readlane((int)suv, k);
            float wk = __int_as_float(__builtin_amdgcn_readlane(__float_as_int(wsv), k));
            w[k] = (k < d) ? wk : 0.f;
            u[k] = h2[(size_t)su * 64 + lane];
        }
#pragma unroll
        for (int k = 0; k < 24; ++k) ACCUM(k)

        // epilogue: masked 8-batches for deg > 24 (d <= BKT by construction)
        for (int e0 = 24; e0 < d; e0 += 8) {
            unsigned u[8];
            float    w[8];
#pragma unroll
            for (int k = 0; k < 8; ++k) {
                int ek  = e0 + k;
                int ekc = ek < (BKT - 1) ? ek : (BKT - 1);
                unsigned su = (unsigned)__builtin_amdgcn_readlane((int)suv, ekc);
                float wk = __int_as_float(__builtin_amdgcn_readlane(__float_as_int(wsv), ekc));
                w[k] = (ek < d) ? wk : 0.f;
                u[k] = h2[(size_t)su * 64 + lane];
            }
#pragma unroll
            for (int k = 0; k < 8; ++k) ACCUM(k)
        }
    }

    float sn = dn * dn;
    unsigned uh = h2[(size_t)n * 64 + lane];
    float2 bb = ((const float2*)b)[lane];
    float2 r;
    r.x = fmaxf((ax0 + ax1) + (ax2 + ax3) + bf2f_lo(uh) * sn + bb.x, 0.f);
    r.y = fmaxf((ay0 + ay1) + (ay2 + ay3) + bf2f_hi(uh) * sn + bb.y, 0.f);
    return r;
}

// ================= fused: agg(conv1) + GEMM(W2) -> Cb, 4 waves = 4 nodes =================
// 256-thread blocks, launch_bounds(256,8): 8-wave granularity -> up to 32 waves/CU
// (vs 16-18 at 512 threads). Occupancy experiment: more waves = more outstanding
// gather misses per CU. MFMA A-tile = 4 real rows + 12 zero; each wave computes
// its two 16-col tiles; only quad-0 lanes store (rows 0-3).
__global__ __launch_bounds__(256, 8) void k_ag4(const unsigned short* __restrict__ Hb_,
                                                const int* __restrict__ degc, const int* __restrict__ esrc,
                                                const float* __restrict__ b1,
                                                const unsigned short* __restrict__ Wt,
                                                unsigned short* __restrict__ Cb) {
    __shared__ __align__(16) unsigned lds[4][64];
    int w = threadIdx.x >> 6, lane = threadIdx.x & 63;
    int n = blockIdx.x * 4 + w;                    // 12500*4 = 50000 exactly
    const unsigned* h2 = (const unsigned*)Hb_;

    float2 r = agg_node(h2, degc, esrc, b1, n, lane);
    lds[w][lane ^ (w << 2)] = (f2bf(r.y) << 16) | f2bf(r.x);
    __syncthreads();

    int quad = lane >> 4, l16 = lane & 15, kx = l16 & 3;
    const unsigned* rowp = &lds[kx][0];            // row = l16 & 3 (dup reads broadcast)
    s8v a0 = *(const s8v*)(rowp + (( 0 + quad) ^ kx) * 4);
    s8v a1 = *(const s8v*)(rowp + (( 4 + quad) ^ kx) * 4);
    s8v a2 = *(const s8v*)(rowp + (( 8 + quad) ^ kx) * 4);
    s8v a3 = *(const s8v*)(rowp + ((12 + quad) ^ kx) * 4);
    if (l16 >= 4) { a0 = (s8v)0; a1 = (s8v)0; a2 = (s8v)0; a3 = (s8v)0; }

    int row0 = blockIdx.x * 4;
#pragma unroll
    for (int t = 0; t < 2; ++t) {                  // two 16-col tiles per wave
        int c = w * 2 + t;
        const s8v* wp = (const s8v*)(Wt + (size_t)(c * 16 + l16) * 128);
        f4v acc = (f4v)0.f;
        acc = __builtin_amdgcn_mfma_f32_16x16x32_bf16(a0, wp[quad],      acc, 0, 0, 0);
        acc = __builtin_amdgcn_mfma_f32_16x16x32_bf16(a1, wp[4 + quad],  acc, 0, 0, 0);
        acc = __builtin_amdgcn_mfma_f32_16x16x32_bf16(a2, wp[8 + quad],  acc, 0, 0, 0);
        acc = __builtin_amdgcn_mfma_f32_16x16x32_bf16(a3, wp[12 + quad], acc, 0, 0, 0);
        if (quad == 0) {                           // rows 0-3 live in quad 0
#pragma unroll
            for (int r2 = 0; r2 < 4; ++r2)
                Cb[(size_t)(row0 + r2) * 128 + c * 16 + l16] = (unsigned short)f2bf(acc[r2]);
        }
    }
}

// ================= fused: agg(conv2) + final projection -> fp32 out =================
__global__ __launch_bounds__(256, 8) void k_af4(const unsigned short* __restrict__ Hb_,
                                                const int* __restrict__ degc, const int* __restrict__ esrc,
                                                const float* __restrict__ b2,
                                                const unsigned short* __restrict__ Wt,
                                                const float* __restrict__ bmu, const float* __restrict__ blv,
                                                float* __restrict__ out) {
    __shared__ __align__(16) unsigned lds[4][64];
    int w = threadIdx.x >> 6, lane = threadIdx.x & 63;
    int n = blockIdx.x * 4 + w;
    const unsigned* h2 = (const unsigned*)Hb_;

    float2 r = agg_node(h2, degc, esrc, b2, n, lane);
    lds[w][lane ^ (w << 2)] = (f2bf(r.y) << 16) | f2bf(r.x);
    __syncthreads();

    int quad = lane >> 4, l16 = lane & 15, kx = l16 & 3;
    const unsigned* rowp = &lds[kx][0];
    s8v a0 = *(const s8v*)(rowp + (( 0 + quad) ^ kx) * 4);
    s8v a1 = *(const s8v*)(rowp + (( 4 + quad) ^ kx) * 4);
    s8v a2 = *(const s8v*)(rowp + (( 8 + quad) ^ kx) * 4);
    s8v a3 = *(const s8v*)(rowp + ((12 + quad) ^ kx) * 4);
    if (l16 >= 4) { a0 = (s8v)0; a1 = (s8v)0; a2 = (s8v)0; a3 = (s8v)0; }

    int row0 = blockIdx.x * 4;
#pragma unroll
    for (int t = 0; t < 2; ++t) {
        int c = w * 2 + t;
        int col = c * 16 + l16;
        const s8v* wp = (const s8v*)(Wt + (size_t)(c * 16 + l16) * 128);
        f4v acc = (f4v)0.f;
        acc = __builtin_amdgcn_mfma_f32_16x16x32_bf16(a0, wp[quad],      acc, 0, 0, 0);
        acc = __builtin_amdgcn_mfma_f32_16x16x32_bf16(a1, wp[4 + quad],  acc, 0, 0, 0);
        acc = __builtin_amdgcn_mfma_f32_16x16x32_bf16(a2, wp[8 + quad],  acc, 0, 0, 0);
        acc = __builtin_amdgcn_mfma_f32_16x16x32_bf16(a3, wp[12 + quad], acc, 0, 0, 0);
        if (quad == 0) {
            float bb = (col < 64) ? bmu[col] : blv[col - 64];
#pragma unroll
            for (int r2 = 0; r2 < 4; ++r2) {
                int ro = row0 + r2;
                float v = acc[r2] + bb;
                if (col < 64) out[(size_t)ro * 64 + col] = v;
                else          out[(size_t)NN * 64 + (size_t)ro * 64 + (col - 64)] = v;
            }
        }
    }
}

extern "C" void kernel_launch(void* const* d_in, const int* in_sizes, int n_in,
                              void* d_out, int out_size, void* d_ws, size_t ws_size,
                              hipStream_t stream) {
    const float* x    = (const float*)d_in[0];
    const int*   eidx = (const int*)d_in[1];
    const float* W1   = (const float*)d_in[2];
    const float* b1   = (const float*)d_in[3];
    const float* W2   = (const float*)d_in[4];
    const float* b2   = (const float*)d_in[5];
    const float* Wmu  = (const float*)d_in[6];
    const float* bmu  = (const float*)d_in[7];
    const float* Wlv  = (const float*)d_in[8];
    const float* blv  = (const float*)d_in[9];
    float* out = (float*)d_out;

    const int* src = eidx;        // edge_index[0]
    const int* dst = eidx + NE;   // edge_index[1]

    // workspace layout (4-byte units)
    float*          ws     = (float*)d_ws;
    int*            cursor = (int*)ws;                         // 50048 (becomes degree)
    int*            esrc   = (int*)(ws + 50048);               // 50000*48 ints + pad
    unsigned short* Wt     = (unsigned short*)(ws + 2450176);  // 2*16384 bf16 (W2t, Wpt)
    unsigned short* Hb     = (unsigned short*)(ws + 2466560);  // 6.4M bf16
    unsigned short* Hb2    = (unsigned short*)(ws + 5666560);  // 6.4M bf16

    const int gFG = 7038 + 128;  // 6256 fill + 782 gemm (8:1 interleave) + 128 Wt transpose
    const int gA  = 12500;       // 4 nodes/block, 256 threads

    // ---- cursor = 0 (stream-ordered, graph-capturable) ----
    hipMemsetAsync(cursor, 0, 50048 * sizeof(int), stream);

    // ---- bucket CSR fill <-> conv1 GEMM | W2/proj transpose ----
    k_fg<<<gFG, 256, 0, stream>>>((const float4*)x, W1, Hb, src, dst, cursor, esrc,
                                  W2, Wmu, Wlv, Wt);

    // ---- conv1 agg fused with conv2 GEMM ----
    k_ag4<<<gA, 256, 0, stream>>>(Hb, cursor, esrc, b1, Wt, Hb2);

    // ---- conv2 agg fused with final projection ----
    k_af4<<<gA, 256, 0, stream>>>(Hb2, cursor, esrc, b2, Wt + 16384, bmu, blv, out);
}

// Round 12
// 233.295 us; speedup vs baseline: 1.1326x; 1.1326x over previous
//
#include <hip/hip_runtime.h>

#define NN 50000
#define NE 800000
#define BKT 48        // bucket slots per node (dataset max in-degree ~45; guarded)

typedef short s8v  __attribute__((ext_vector_type(8)));   // 8 bf16 (4 VGPRs)
typedef float f4v  __attribute__((ext_vector_type(4)));   // MFMA acc

__device__ __forceinline__ unsigned f2bf(float f) {       // RNE pack
    unsigned u = __float_as_uint(f);
    return (u + 0x7fffu + ((u >> 16) & 1u)) >> 16;
}
__device__ __forceinline__ float bf2f_lo(unsigned u) { return __uint_as_float(u << 16); }
__device__ __forceinline__ float bf2f_hi(unsigned u) { return __uint_as_float(u & 0xffff0000u); }

__device__ __forceinline__ s8v pack8(float4 p, float4 q) {
    union { unsigned u[4]; s8v v; } r;
    r.u[0] = (f2bf(p.y) << 16) | f2bf(p.x);
    r.u[1] = (f2bf(p.w) << 16) | f2bf(p.z);
    r.u[2] = (f2bf(q.y) << 16) | f2bf(q.x);
    r.u[3] = (f2bf(q.w) << 16) | f2bf(q.z);
    return r.v;
}

// Build MFMA B-fragment in-register from fp32 W (used ONLY in k_fg's GEMM blocks,
// which have VGPR/latency slack; NOT in the agg kernels where it costs occupancy).
__device__ __forceinline__ s8v wfrag(const float* __restrict__ W, int ldw, int n, int kc) {
    const float* p = W + (size_t)kc * 8 * ldw + n;
    union { unsigned u[4]; s8v v; } r;
#pragma unroll
    for (int t = 0; t < 4; ++t)
        r.u[t] = (f2bf(p[(size_t)(2 * t + 1) * ldw]) << 16) | f2bf(p[(size_t)(2 * t) * ldw]);
    return r.v;
}

// ================= fused + INTERLEAVED: single-pass bucket fill <-> GEMM-1 | Wt transpose =================
// blocks [0,1564): even = fill (int4, 4 edges/thread, ONE pass over the edge list —
// remote atomics pipeline and hide under the co-resident GEMM waves), odd = GEMM.
// blocks [1564,1692): transpose W2/proj -> bf16 Wt (consumed by the NEXT kernels).
__global__ __launch_bounds__(256) void k_fg(const float4* __restrict__ x4,
                                            const float* __restrict__ W1,
                                            unsigned short* __restrict__ Hb,
                                            const int* __restrict__ src, const int* __restrict__ dst,
                                            int* __restrict__ cursor, int* __restrict__ esrc,
                                            const float* __restrict__ W2,
                                            const float* __restrict__ Wmu, const float* __restrict__ Wlv,
                                            unsigned short* __restrict__ Wt) {
    int b = blockIdx.x;
    if (b >= 1564) {
        int idx = (b - 1564) * 256 + (int)threadIdx.x;   // < 32768 = 2*16384 exactly
        int m = idx >> 14, i = idx & 16383;
        int n = i & 127, k = i >> 7;
        float v;
        if (m == 0) v = W2[k * 128 + n];
        else        v = (n < 64) ? Wmu[k * 64 + n] : Wlv[k * 64 + (n - 64)];
        Wt[m * 16384 + n * 128 + k] = (unsigned short)f2bf(v);
        return;
    }
    if ((b & 1) == 0) {
        int idx = (b >> 1) * 256 + (int)threadIdx.x;     // 782*256 = 200192 >= 200000
        if (idx >= NE / 4) return;
        int4 d4 = ((const int4*)dst)[idx];
        int4 s4 = ((const int4*)src)[idx];
        int dv[4] = { d4.x, d4.y, d4.z, d4.w };
        int sv[4] = { s4.x, s4.y, s4.z, s4.w };
#pragma unroll
        for (int k = 0; k < 4; ++k) {
            int p = atomicAdd(&cursor[dv[k]], 1);        // avg 16/cursor: low contention
            if (p < BKT) esrc[(size_t)dv[k] * BKT + p] = sv[k];
        }
    } else {
        int bg = b >> 1;                           // gemm index [0, 782)
        int wave = threadIdx.x >> 6, lane = threadIdx.x & 63;
        int quad = lane >> 4, l16 = lane & 15;
        int row0 = bg * 64 + wave * 16;
        int arow = row0 + l16;
        int arc  = arow < NN ? arow : NN - 1;      // clamp (stores guarded)

        const float4* xq = x4 + (size_t)arc * 32;  // 32 float4 per 128-ch row
        s8v a0 = pack8(xq[ 0 + quad * 2], xq[ 1 + quad * 2]);
        s8v a1 = pack8(xq[ 8 + quad * 2], xq[ 9 + quad * 2]);
        s8v a2 = pack8(xq[16 + quad * 2], xq[17 + quad * 2]);
        s8v a3 = pack8(xq[24 + quad * 2], xq[25 + quad * 2]);

        f4v acc[8];
#pragma unroll
        for (int c = 0; c < 8; ++c) acc[c] = (f4v)0.f;

#pragma unroll
        for (int c = 0; c < 8; ++c) {
            int n = c * 16 + l16;
            s8v w0 = wfrag(W1, 128, n, quad);
            s8v w1 = wfrag(W1, 128, n, 4 + quad);
            s8v w2 = wfrag(W1, 128, n, 8 + quad);
            s8v w3 = wfrag(W1, 128, n, 12 + quad);
            acc[c] = __builtin_amdgcn_mfma_f32_16x16x32_bf16(a0, w0, acc[c], 0, 0, 0);
            acc[c] = __builtin_amdgcn_mfma_f32_16x16x32_bf16(a1, w1, acc[c], 0, 0, 0);
            acc[c] = __builtin_amdgcn_mfma_f32_16x16x32_bf16(a2, w2, acc[c], 0, 0, 0);
            acc[c] = __builtin_amdgcn_mfma_f32_16x16x32_bf16(a3, w3, acc[c], 0, 0, 0);
        }

#pragma unroll
        for (int c = 0; c < 8; ++c) {
#pragma unroll
            for (int r = 0; r < 4; ++r) {
                int ro = row0 + quad * 4 + r;
                if (ro < NN) Hb[(size_t)ro * 128 + c * 16 + l16] = (unsigned short)f2bf(acc[c][r]);
            }
        }
    }
}

#define ACCUM(K) { float lo = bf2f_lo(u[K]), hi = bf2f_hi(u[K]);            \
    switch ((K) & 3) {                                                       \
        case 0: ax0 += lo * w[K]; ay0 += hi * w[K]; break;                   \
        case 1: ax1 += lo * w[K]; ay1 += hi * w[K]; break;                   \
        case 2: ax2 += lo * w[K]; ay2 += hi * w[K]; break;                   \
        default: ax3 += lo * w[K]; ay3 += hi * w[K]; break; } }

// ================= per-node aggregation (one full wave per node) — R6-proven =================
__device__ __forceinline__ float2 agg_node(const unsigned* __restrict__ h2,
                                           const int* __restrict__ degc,
                                           const int* __restrict__ esrc,
                                           const float* __restrict__ b,
                                           int n, int lane) {
    int d = __builtin_amdgcn_readfirstlane(degc[n]);
    float dn = rsqrtf((float)(d + 1));             // +1 = self loop
    int svr = esrc[(size_t)n * BKT + lane];        // whole bucket (lanes >= BKT spill into
                                                   // next bucket; only lanes < d consumed)
    unsigned suv = ((unsigned)svr < (unsigned)NN) ? (unsigned)svr : 0u;  // clamp garbage
    int dgv = degc[suv];                           // per-lane degree gather (64 parallel)
    float wsv = rsqrtf((float)(dgv + 1)) * dn;     // per-lane edge weight

    float ax0 = 0.f, ay0 = 0.f, ax1 = 0.f, ay1 = 0.f;
    float ax2 = 0.f, ay2 = 0.f, ax3 = 0.f, ay3 = 0.f;

    if (d <= 16) {   // short prologue: 16 masked gathers
        unsigned u[16];
        float    w[16];
#pragma unroll
        for (int k = 0; k < 16; ++k) {
            unsigned su = (unsigned)__builtin_amdgcn_readlane((int)suv, k);
            float wk = __int_as_float(__builtin_amdgcn_readlane(__float_as_int(wsv), k));
            w[k] = (k < d) ? wk : 0.f;
            u[k] = h2[(size_t)su * 64 + lane];
        }
#pragma unroll
        for (int k = 0; k < 16; ++k) ACCUM(k)
    } else {         // 24 masked gathers, all independent
        unsigned u[24];
        float    w[24];
#pragma unroll
        for (int k = 0; k < 24; ++k) {
            unsigned su = (unsigned)__builtin_amdgcn_readlane((int)suv, k);
            float wk = __int_as_float(__builtin_amdgcn_readlane(__float_as_int(wsv), k));
            w[k] = (k < d) ? wk : 0.f;
            u[k] = h2[(size_t)su * 64 + lane];
        }
#pragma unroll
        for (int k = 0; k < 24; ++k) ACCUM(k)

        // epilogue: masked 8-batches for deg > 24 (d <= BKT by construction)
        for (int e0 = 24; e0 < d; e0 += 8) {
            unsigned u[8];
            float    w[8];
#pragma unroll
            for (int k = 0; k < 8; ++k) {
                int ek  = e0 + k;
                int ekc = ek < (BKT - 1) ? ek : (BKT - 1);
                unsigned su = (unsigned)__builtin_amdgcn_readlane((int)suv, ekc);
                float wk = __int_as_float(__builtin_amdgcn_readlane(__float_as_int(wsv), ekc));
                w[k] = (ek < d) ? wk : 0.f;
                u[k] = h2[(size_t)su * 64 + lane];
            }
#pragma unroll
            for (int k = 0; k < 8; ++k) ACCUM(k)
        }
    }

    float sn = dn * dn;
    unsigned uh = h2[(size_t)n * 64 + lane];
    float2 bb = ((const float2*)b)[lane];
    float2 r;
    r.x = fmaxf((ax0 + ax1) + (ax2 + ax3) + bf2f_lo(uh) * sn + bb.x, 0.f);
    r.y = fmaxf((ay0 + ay1) + (ay2 + ay3) + bf2f_hi(uh) * sn + bb.y, 0.f);
    return r;
}

// ================= fused: agg(conv1) + GEMM(W2) -> Cb, 8 waves = 8 nodes (R10 form) =================
__global__ __launch_bounds__(512, 4) void k_ag8(const unsigned short* __restrict__ Hb_,
                                                const int* __restrict__ degc, const int* __restrict__ esrc,
                                                const float* __restrict__ b1,
                                                const unsigned short* __restrict__ Wt,
                                                unsigned short* __restrict__ Cb) {
    __shared__ __align__(16) unsigned lds[8][64];
    int w = threadIdx.x >> 6, lane = threadIdx.x & 63;
    int n = blockIdx.x * 8 + w;                    // 6250*8 = 50000 exactly
    const unsigned* h2 = (const unsigned*)Hb_;

    float2 r = agg_node(h2, degc, esrc, b1, n, lane);
    lds[w][lane ^ (w << 2)] = (f2bf(r.y) << 16) | f2bf(r.x);
    __syncthreads();

    int quad = lane >> 4, l16 = lane & 15, kx = l16 & 7;
    const unsigned* rowp = &lds[l16 & 7][0];
    s8v a0 = *(const s8v*)(rowp + (( 0 + quad) ^ kx) * 4);
    s8v a1 = *(const s8v*)(rowp + (( 4 + quad) ^ kx) * 4);
    s8v a2 = *(const s8v*)(rowp + (( 8 + quad) ^ kx) * 4);
    s8v a3 = *(const s8v*)(rowp + ((12 + quad) ^ kx) * 4);
    if (l16 >= 8) { a0 = (s8v)0; a1 = (s8v)0; a2 = (s8v)0; a3 = (s8v)0; }

    const s8v* wp = (const s8v*)(Wt + (size_t)(w * 16 + l16) * 128);
    f4v acc = (f4v)0.f;
    acc = __builtin_amdgcn_mfma_f32_16x16x32_bf16(a0, wp[quad],      acc, 0, 0, 0);
    acc = __builtin_amdgcn_mfma_f32_16x16x32_bf16(a1, wp[4 + quad],  acc, 0, 0, 0);
    acc = __builtin_amdgcn_mfma_f32_16x16x32_bf16(a2, wp[8 + quad],  acc, 0, 0, 0);
    acc = __builtin_amdgcn_mfma_f32_16x16x32_bf16(a3, wp[12 + quad], acc, 0, 0, 0);

    int row0 = blockIdx.x * 8;
#pragma unroll
    for (int r2 = 0; r2 < 4; ++r2) {
        int ro8 = quad * 4 + r2;
        if (ro8 < 8)
            Cb[(size_t)(row0 + ro8) * 128 + w * 16 + l16] = (unsigned short)f2bf(acc[r2]);
    }
}

// ================= fused: agg(conv2) + final projection -> fp32 out (R10 form) =================
__global__ __launch_bounds__(512, 4) void k_af8(const unsigned short* __restrict__ Hb_,
                                                const int* __restrict__ degc, const int* __restrict__ esrc,
                                                const float* __restrict__ b2,
                                                const unsigned short* __restrict__ Wt,
                                                const float* __restrict__ bmu, const float* __restrict__ blv,
                                                float* __restrict__ out) {
    __shared__ __align__(16) unsigned lds[8][64];
    int w = threadIdx.x >> 6, lane = threadIdx.x & 63;
    int n = blockIdx.x * 8 + w;
    const unsigned* h2 = (const unsigned*)Hb_;

    float2 r = agg_node(h2, degc, esrc, b2, n, lane);
    lds[w][lane ^ (w << 2)] = (f2bf(r.y) << 16) | f2bf(r.x);
    __syncthreads();

    int quad = lane >> 4, l16 = lane & 15, kx = l16 & 7;
    const unsigned* rowp = &lds[l16 & 7][0];
    s8v a0 = *(const s8v*)(rowp + (( 0 + quad) ^ kx) * 4);
    s8v a1 = *(const s8v*)(rowp + (( 4 + quad) ^ kx) * 4);
    s8v a2 = *(const s8v*)(rowp + (( 8 + quad) ^ kx) * 4);
    s8v a3 = *(const s8v*)(rowp + ((12 + quad) ^ kx) * 4);
    if (l16 >= 8) { a0 = (s8v)0; a1 = (s8v)0; a2 = (s8v)0; a3 = (s8v)0; }

    const s8v* wp = (const s8v*)(Wt + (size_t)(w * 16 + l16) * 128);
    f4v acc = (f4v)0.f;
    acc = __builtin_amdgcn_mfma_f32_16x16x32_bf16(a0, wp[quad],      acc, 0, 0, 0);
    acc = __builtin_amdgcn_mfma_f32_16x16x32_bf16(a1, wp[4 + quad],  acc, 0, 0, 0);
    acc = __builtin_amdgcn_mfma_f32_16x16x32_bf16(a2, wp[8 + quad],  acc, 0, 0, 0);
    acc = __builtin_amdgcn_mfma_f32_16x16x32_bf16(a3, wp[12 + quad], acc, 0, 0, 0);

    int row0 = blockIdx.x * 8;
    int col  = w * 16 + l16;
    float bb = (col < 64) ? bmu[col] : blv[col - 64];
#pragma unroll
    for (int r2 = 0; r2 < 4; ++r2) {
        int ro8 = quad * 4 + r2;
        if (ro8 < 8) {
            int ro = row0 + ro8;
            float v = acc[r2] + bb;
            if (col < 64) out[(size_t)ro * 64 + col] = v;
            else          out[(size_t)NN * 64 + (size_t)ro * 64 + (col - 64)] = v;
        }
    }
}

extern "C" void kernel_launch(void* const* d_in, const int* in_sizes, int n_in,
                              void* d_out, int out_size, void* d_ws, size_t ws_size,
                              hipStream_t stream) {
    const float* x    = (const float*)d_in[0];
    const int*   eidx = (const int*)d_in[1];
    const float* W1   = (const float*)d_in[2];
    const float* b1   = (const float*)d_in[3];
    const float* W2   = (const float*)d_in[4];
    const float* b2   = (const float*)d_in[5];
    const float* Wmu  = (const float*)d_in[6];
    const float* bmu  = (const float*)d_in[7];
    const float* Wlv  = (const float*)d_in[8];
    const float* blv  = (const float*)d_in[9];
    float* out = (float*)d_out;

    const int* src = eidx;        // edge_index[0]
    const int* dst = eidx + NE;   // edge_index[1]

    // workspace layout (4-byte units)
    float*          ws     = (float*)d_ws;
    int*            cursor = (int*)ws;                         // 50048 (becomes degree)
    int*            esrc   = (int*)(ws + 50048);               // 50000*48 ints + pad
    unsigned short* Wt     = (unsigned short*)(ws + 2450176);  // 2*16384 bf16 (W2t, Wpt)
    unsigned short* Hb     = (unsigned short*)(ws + 2466560);  // 6.4M bf16
    unsigned short* Hb2    = (unsigned short*)(ws + 5666560);  // 6.4M bf16

    const int gFG = 1564 + 128;  // 782 fill + 782 gemm (1:1 interleave) + 128 Wt transpose
    const int gA  = 6250;        // 8 nodes/block, 512 threads

    // ---- cursor = 0 (stream-ordered, graph-capturable) ----
    hipMemsetAsync(cursor, 0, 50048 * sizeof(int), stream);

    // ---- single-pass bucket fill <-> conv1 GEMM | W2/proj transpose ----
    k_fg<<<gFG, 256, 0, stream>>>((const float4*)x, W1, Hb, src, dst, cursor, esrc,
                                  W2, Wmu, Wlv, Wt);

    // ---- conv1 agg fused with conv2 GEMM ----
    k_ag8<<<gA, 512, 0, stream>>>(Hb, cursor, esrc, b1, Wt, Hb2);

    // ---- conv2 agg fused with final projection ----
    k_af8<<<gA, 512, 0, stream>>>(Hb2, cursor, esrc, b2, Wt + 16384, bmu, blv, out);
}